// Round 5
// baseline (846.982 us; speedup 1.0000x reference)
//
#include <hip/hip_runtime.h>

// B=2,S=2048 -> T=4096 tokens, D=1024, F=4096, E=8; top_k on device.
// fp32 I/O; bf16 MFMA compute (fp32 accumulate).
// R10: BK=64 windows (2 K-tiles per barrier pair, halves sync overhead),
// 2x64KB LDS buffers, counted vmcnt(8) w/ clobber-free waits + sched_barrier
// fences; gemm2 de-atomic'd -> Y0/Y1 + combine kernel (weights applied
// there); compact H/Y rows via per-expert roff; 3-bit XOR LDS swizzle for
// 128B rows (conflict-free ds_read_b128).
#define T_TOK 4096
#define DIM   1024
#define FDIM  4096
#define NEXP  8
#define PADROWS 10240   // >= 8192 + 8*255

typedef __bf16 bf16x8 __attribute__((ext_vector_type(8)));
typedef __bf16 bf16x4 __attribute__((ext_vector_type(4)));
typedef float  f32x4  __attribute__((ext_vector_type(4)));
typedef const __attribute__((address_space(3))) char* lds3;

__device__ __forceinline__ void glds16(const void* g, void* l) {
    __builtin_amdgcn_global_load_lds(
        (const __attribute__((address_space(1))) void*)g,
        (__attribute__((address_space(3))) void*)l, 16, 0, 0);
}

// Clobber-free: SIInsertWaitcnts must not see a mayLoad/mayStore asm, else
// it inserts vmcnt(0) drains that nullify the counted pipeline (R7/R8 bug).
#define DSR(dst, a, imm) \
    asm volatile("ds_read_b128 %0, %1 offset:" #imm : "=v"(dst) : "v"(a))

// Bijective XCD-chunking swizzle (m204).
__device__ __forceinline__ int xcd_swz(int phys, int total) {
    int q = total >> 3, r = total & 7;
    int x = phys & 7, i = phys >> 3;
    return (x < r ? x * (q + 1) : r * (q + 1) + (x - r) * q) + i;
}

// ---------------------------------------------------------------------------
// Router (+ x->bf16 convert): one wave per token.
// ---------------------------------------------------------------------------
__global__ __launch_bounds__(64)
void moe_router(const float* __restrict__ x,
                const float* __restrict__ gw,
                const float* __restrict__ gb,
                const int*   __restrict__ topk_p,
                int*   __restrict__ counts,
                int*   __restrict__ bucket,
                int*   __restrict__ slot,
                float* __restrict__ tw,
                __bf16* __restrict__ xb) {
    const int t = blockIdx.x;
    const int lane = threadIdx.x;
    float part[NEXP];
#pragma unroll
    for (int e = 0; e < NEXP; ++e) part[e] = 0.f;
    const float* xrow = x + (size_t)t * DIM;
    __bf16* xbrow = xb + (size_t)t * DIM;
#pragma unroll
    for (int r = 0; r < 4; ++r) {
        int c = r * 256 + lane * 4;
        float4 v = *(const float4*)&xrow[c];
        bf16x4 o; o[0]=(__bf16)v.x; o[1]=(__bf16)v.y; o[2]=(__bf16)v.z; o[3]=(__bf16)v.w;
        *(bf16x4*)&xbrow[c] = o;
#pragma unroll
        for (int e = 0; e < NEXP; ++e) {
            float4 g = *(const float4*)&gw[e * DIM + c];
            part[e] += v.x*g.x + v.y*g.y + v.z*g.z + v.w*g.w;
        }
    }
#pragma unroll
    for (int off = 32; off > 0; off >>= 1) {
#pragma unroll
        for (int e = 0; e < NEXP; ++e) part[e] += __shfl_xor(part[e], off);
    }
    if (lane == 0) {
        int k = topk_p[0];
        if (k < 1) k = 1;
        if (k > NEXP) k = NEXP;
        float p[NEXP];
        float mx = -1e30f;
#pragma unroll
        for (int e = 0; e < NEXP; ++e) {
            p[e] = part[e] + gb[e];
            mx = fmaxf(mx, p[e]);
        }
#pragma unroll
        for (int e = 0; e < NEXP; ++e) p[e] = __expf(p[e] - mx);
        bool used[NEXP];
#pragma unroll
        for (int e = 0; e < NEXP; ++e) used[e] = false;
        int sel[NEXP]; float selp[NEXP]; float wsum = 0.f;
        for (int j = 0; j < k; ++j) {
            int best = 0; float bv = -1.f;
            for (int e = 0; e < NEXP; ++e)
                if (!used[e] && p[e] > bv) { bv = p[e]; best = e; }  // ties->low idx
            used[best] = true; sel[j] = best; selp[j] = bv; wsum += bv;
        }
        for (int j = 0; j < k; ++j) {
            int e = sel[j];
            int pos = atomicAdd(&counts[e], 1);
            bucket[e * T_TOK + pos] = t;
            slot[t * 8 + j] = (e << 12) | pos;
            tw[t * 8 + j]   = selp[j] / wsum;
        }
    }
}

// Per-expert transpose+convert: in [z][R][C] fp32 -> out [z][C][R] bf16.
__global__ __launch_bounds__(256)
void transpose_cvt(const float* __restrict__ in, __bf16* __restrict__ out,
                   int R, int C) {
    const size_t zo = (size_t)blockIdx.z * R * C;
    in += zo; out += zo;
    __shared__ float ts[64][65];
    const int c0 = blockIdx.x * 64, r0 = blockIdx.y * 64;
    const int t = threadIdx.x;
    const int rr = t >> 2, cc4 = (t & 3) * 16;
    const float* src = in + (size_t)(r0 + rr) * C + c0 + cc4;
#pragma unroll
    for (int i = 0; i < 4; ++i) {
        float4 v = *(const float4*)(src + i * 4);
        ts[rr][cc4 + i*4 + 0] = v.x; ts[rr][cc4 + i*4 + 1] = v.y;
        ts[rr][cc4 + i*4 + 2] = v.z; ts[rr][cc4 + i*4 + 3] = v.w;
    }
    __syncthreads();
    const int oc = rr, orc = cc4;
    bf16x8 o0, o1;
#pragma unroll
    for (int i = 0; i < 8; ++i) o0[i] = (__bf16)ts[orc + i][oc];
#pragma unroll
    for (int i = 0; i < 8; ++i) o1[i] = (__bf16)ts[orc + 8 + i][oc];
    __bf16* dst = out + (size_t)(c0 + oc) * R + r0 + orc;
    *(bf16x8*)dst = o0;
    *(bf16x8*)(dst + 8) = o1;
}

// ---------------------------------------------------------------------------
// Work list: hdr[0]=n entries; hdr[16+e]=row offset (roff) per expert;
// entries (e<<16)|tile at hdr[32+i].
// ---------------------------------------------------------------------------
__global__ __launch_bounds__(64)
void build_work(const int* __restrict__ counts, int* __restrict__ hdr) {
    __shared__ int off1[NEXP + 1];
    const int lane = threadIdx.x;
    if (lane == 0) {
        int a = 0, rows = 0;
        for (int e = 0; e < NEXP; ++e) {
            off1[e] = a;
            hdr[16 + e] = rows;
            int nt = (counts[e] + 255) >> 8;
            a += nt;
            rows += nt * 256;
        }
        off1[NEXP] = a;
        hdr[0] = a;
    }
    __syncthreads();
    for (int e = 0; e < NEXP; ++e) {
        int n1 = off1[e + 1] - off1[e];
        for (int j = lane; j < n1; j += 64) hdr[32 + off1[e] + j] = (e << 16) | j;
    }
}

// ---------------------------------------------------------------------------
// Shared GEMM geometry: tile 256x256, window BK=64, 8 waves (2M x 4N).
// LDS: 2 windows x (A[256][64] 32KB + B[256][64] 32KB) = 128KB.
// Row = 128B = 8 x 16B chunks; swizzle: LDS slot (r,c) holds data chunk
// c ^ (r&7)  (inverse-swizzled glds16 SOURCE, linear LDS dest; reads XOR
// the same -> conflict-free ds_read_b128).
// Window step: STAGE next (8 glds/wave) -> vmcnt(8) -> s_barrier ->
// 16 DSR / MFMA kk0 / 8 DSR / MFMA kk1 -> s_barrier.
// ---------------------------------------------------------------------------
#define MFMA_CL(AF, BF) do { \
    _Pragma("unroll") for (int i_ = 0; i_ < 8; ++i_) \
    _Pragma("unroll") for (int j_ = 0; j_ < 4; ++j_) \
        acc[i_][j_] = __builtin_amdgcn_mfma_f32_16x16x32_bf16( \
            AF[i_], BF[j_], acc[i_][j_], 0, 0, 0); } while (0)

#define WINBODY(A0, A1, B0, B1) do { \
    bf16x8 af[8], b0r[4], b1r[4]; \
    DSR(af[0],(A0),0);    DSR(af[1],(A0),2048); \
    DSR(af[2],(A0),4096); DSR(af[3],(A0),6144); \
    DSR(af[4],(A0),8192); DSR(af[5],(A0),10240); \
    DSR(af[6],(A0),12288);DSR(af[7],(A0),14336); \
    DSR(b0r[0],(B0),0);   DSR(b0r[1],(B0),2048); \
    DSR(b0r[2],(B0),4096);DSR(b0r[3],(B0),6144); \
    DSR(b1r[0],(B1),0);   DSR(b1r[1],(B1),2048); \
    DSR(b1r[2],(B1),4096);DSR(b1r[3],(B1),6144); \
    asm volatile("s_waitcnt lgkmcnt(4)"); \
    __builtin_amdgcn_sched_barrier(0); \
    __builtin_amdgcn_s_setprio(1); \
    MFMA_CL(af, b0r); \
    __builtin_amdgcn_s_setprio(0); \
    __builtin_amdgcn_sched_barrier(0); \
    DSR(af[0],(A1),0);    DSR(af[1],(A1),2048); \
    DSR(af[2],(A1),4096); DSR(af[3],(A1),6144); \
    DSR(af[4],(A1),8192); DSR(af[5],(A1),10240); \
    DSR(af[6],(A1),12288);DSR(af[7],(A1),14336); \
    asm volatile("s_waitcnt lgkmcnt(0)"); \
    __builtin_amdgcn_sched_barrier(0); \
    __builtin_amdgcn_s_setprio(1); \
    MFMA_CL(af, b1r); \
    __builtin_amdgcn_s_setprio(0); \
    __builtin_amdgcn_sched_barrier(0); } while (0)

#define STAGE8(DST, PA, PB, KO) do { \
    glds16(PA[0]+(KO), (DST));         glds16(PA[1]+(KO), (DST)+8192); \
    glds16(PA[2]+(KO), (DST)+16384);   glds16(PA[3]+(KO), (DST)+24576); \
    glds16(PB[0]+(KO), (DST)+32768);   glds16(PB[1]+(KO), (DST)+40960); \
    glds16(PB[2]+(KO), (DST)+49152);   glds16(PB[3]+(KO), (DST)+57344); } while (0)

#define KLOOP(NW) do { \
    STAGE8(st0, pa, pb, 0); \
    for (int tw_ = 0; tw_ < (NW); tw_ += 2) { \
        STAGE8(st1, pa, pb, (tw_ + 1) * 64); \
        __builtin_amdgcn_sched_barrier(0); \
        asm volatile("s_waitcnt vmcnt(8)"); \
        __builtin_amdgcn_sched_barrier(0); \
        __builtin_amdgcn_s_barrier(); \
        WINBODY(rA00, rA01, rB00, rB01); \
        __builtin_amdgcn_s_barrier(); \
        if (tw_ + 2 < (NW)) { \
            STAGE8(st0, pa, pb, (tw_ + 2) * 64); \
            __builtin_amdgcn_sched_barrier(0); \
            asm volatile("s_waitcnt vmcnt(8)"); \
        } else { \
            asm volatile("s_waitcnt vmcnt(0)"); \
        } \
        __builtin_amdgcn_sched_barrier(0); \
        __builtin_amdgcn_s_barrier(); \
        WINBODY(rA10, rA11, rB10, rB11); \
        __builtin_amdgcn_s_barrier(); \
    } } while (0)

// ---------------------------------------------------------------------------
// GEMM1: H[grow,f] = silu( xb[tok].W1T[e][f][:] + b1[e][f] )
// ---------------------------------------------------------------------------
__global__ __launch_bounds__(512, 2)
void moe_gemm1(const __bf16* __restrict__ xb,
               const __bf16* __restrict__ w1t,   // [E][F][D]
               const float*  __restrict__ b1,
               const int*    __restrict__ counts,
               const int*    __restrict__ bucket,
               const int*    __restrict__ hdr,
               __bf16* __restrict__ H) {
    __shared__ __align__(16) char sb[2 * 65536];   // 128KB
    __shared__ int tok_s[256];
    const int tid = threadIdx.x;
    const int wave = tid >> 6, lane = tid & 63;
    const int wm = wave & 1, wn = wave >> 1;
    const int quad = lane >> 4, l15 = lane & 15;
    const int lrow = lane >> 2;
    const int srcoff = ((lane & 7) ^ ((lane >> 3) & 7)) * 8;  // inv-swz elems
    char* st0 = sb + wave * 1024;
    char* st1 = sb + 65536 + wave * 1024;
    lds3 s3 = (lds3)sb;
    const int arow = (wm * 128 + l15) * 128;
    const int brow = 32768 + (wn * 64 + l15) * 128;
    const int ch0 = ((quad     ^ (l15 & 7)) << 4);
    const int ch1 = (((4+quad) ^ (l15 & 7)) << 4);
    lds3 rA00 = s3 + arow + ch0,          rA01 = s3 + arow + ch1;
    lds3 rB00 = s3 + brow + ch0,          rB01 = s3 + brow + ch1;
    lds3 rA10 = rA00 + 65536,             rA11 = rA01 + 65536;
    lds3 rB10 = rB00 + 65536,             rB11 = rB01 + 65536;

    const int n1 = hdr[0];
    const int total = n1 * (FDIM / 256);
    for (int phys = blockIdx.x; phys < total; phys += gridDim.x) {
        const int u = xcd_swz(phys, total);
        const int entry = hdr[32 + (u % n1)];
        const int e = entry >> 16, tile = entry & 0xffff;
        const int nb = (u / n1) * 256;
        const int cnt = counts[e];
        const int grow0 = hdr[16 + e] + tile * 256;
        if (tid < 256) {
            int rw = tile * 256 + tid;
            if (rw >= cnt) rw = cnt - 1;
            tok_s[tid] = bucket[e * T_TOK + rw];
        }
        __syncthreads();

        const __bf16* pa[4];
        const __bf16* pb[4];
#pragma unroll
        for (int q = 0; q < 4; ++q) {
            int rq = q * 64 + wave * 8 + (lane >> 3);
            pa[q] = xb + (size_t)tok_s[rq] * DIM + srcoff;
            pb[q] = w1t + ((size_t)e * FDIM + nb + rq) * DIM + srcoff;
        }

        f32x4 acc[8][4];
#pragma unroll
        for (int i = 0; i < 8; ++i)
#pragma unroll
            for (int j = 0; j < 4; ++j) acc[i][j] = (f32x4){0.f,0.f,0.f,0.f};

        KLOOP(16);   // K = DIM = 16 windows of 64

        // Epilogue: wave-private LDS transpose -> b128 H stores (compact rows).
        __bf16* stg = (__bf16*)(sb + wave * 2304);
        const float* b1e = b1 + e * FDIM + nb + wn * 64;
#pragma unroll
        for (int i = 0; i < 8; ++i) {
#pragma unroll
            for (int j = 0; j < 4; ++j) {
                float bias = b1e[j * 16 + l15];
#pragma unroll
                for (int r = 0; r < 4; ++r) {
                    float v = acc[i][j][r] + bias;
                    float s = v / (1.f + __expf(-v));   // silu
                    stg[(quad*4 + r) * 72 + j*16 + l15] = (__bf16)s;
                }
            }
            int grow = grow0 + wm * 128 + i * 16 + lrow;
            bf16x8 v0 = *(const bf16x8*)&stg[lrow * 72 + (lane & 3) * 16];
            bf16x8 v1 = *(const bf16x8*)&stg[lrow * 72 + (lane & 3) * 16 + 8];
            __bf16* dst = H + (size_t)grow * FDIM + nb + wn * 64 + (lane & 3) * 16;
            *(bf16x8*)dst = v0;
            *(bf16x8*)(dst + 8) = v1;
        }
        __syncthreads();
    }
}

// ---------------------------------------------------------------------------
// GEMM2: Y[kc][grow,d] = H[grow,:kc-half].W2T[e][d][:] (+ b2 if kc==0)
// Non-atomic: combine kernel applies gate weights and sums.
// ---------------------------------------------------------------------------
#define KSPLIT 2
#define KHALF  (FDIM / KSPLIT)

__global__ __launch_bounds__(512, 2)
void moe_gemm2(const __bf16* __restrict__ H,
               const __bf16* __restrict__ w2t,   // [E][D][F]
               const float*  __restrict__ b2,
               const int*    __restrict__ hdr,
               __bf16* __restrict__ Y0,
               __bf16* __restrict__ Y1) {
    __shared__ __align__(16) char sb[2 * 65536];
    const int tid = threadIdx.x;
    const int wave = tid >> 6, lane = tid & 63;
    const int wm = wave & 1, wn = wave >> 1;
    const int quad = lane >> 4, l15 = lane & 15;
    const int lrow = lane >> 2;
    const int srcoff = ((lane & 7) ^ ((lane >> 3) & 7)) * 8;
    char* st0 = sb + wave * 1024;
    char* st1 = sb + 65536 + wave * 1024;
    lds3 s3 = (lds3)sb;
    const int arow = (wm * 128 + l15) * 128;
    const int brow = 32768 + (wn * 64 + l15) * 128;
    const int ch0 = ((quad     ^ (l15 & 7)) << 4);
    const int ch1 = (((4+quad) ^ (l15 & 7)) << 4);
    lds3 rA00 = s3 + arow + ch0,          rA01 = s3 + arow + ch1;
    lds3 rB00 = s3 + brow + ch0,          rB01 = s3 + brow + ch1;
    lds3 rA10 = rA00 + 65536,             rA11 = rA01 + 65536;
    lds3 rB10 = rB00 + 65536,             rB11 = rB01 + 65536;

    const int n1 = hdr[0];
    const int total = n1 * (DIM / 256) * KSPLIT;
    for (int phys = blockIdx.x; phys < total; phys += gridDim.x) {
        const int u = xcd_swz(phys, total);
        const int entry = hdr[32 + (u % n1)];
        const int e = entry >> 16, tile = entry & 0xffff;
        const int rest = u / n1;
        const int nb = (rest & 3) * 256;
        const int kc = rest >> 2;
        const int grow0 = hdr[16 + e] + tile * 256;
        const size_t kbase = (size_t)kc * KHALF;

        const __bf16* pa[4];
        const __bf16* pb[4];
#pragma unroll
        for (int q = 0; q < 4; ++q) {
            int rq = q * 64 + wave * 8 + (lane >> 3);
            pa[q] = H + (size_t)(grow0 + rq) * FDIM + kbase + srcoff;
            pb[q] = w2t + ((size_t)e * DIM + nb + rq) * FDIM + kbase + srcoff;
        }

        f32x4 acc[8][4];
#pragma unroll
        for (int i = 0; i < 8; ++i)
#pragma unroll
            for (int j = 0; j < 4; ++j) acc[i][j] = (f32x4){0.f,0.f,0.f,0.f};

        __syncthreads();   // protect LDS reuse across units; drains vmcnt

        KLOOP(32);   // K = KHALF = 32 windows of 64

        __bf16* Y = kc == 0 ? Y0 : Y1;
        __bf16* stg = (__bf16*)(sb + wave * 2304);
        const float* b2e = b2 + e * DIM + nb + wn * 64;
#pragma unroll
        for (int i = 0; i < 8; ++i) {
#pragma unroll
            for (int j = 0; j < 4; ++j) {
                float bias = (kc == 0) ? b2e[j * 16 + l15] : 0.f;
#pragma unroll
                for (int r = 0; r < 4; ++r) {
                    float v = acc[i][j][r] + bias;
                    stg[(quad*4 + r) * 72 + j*16 + l15] = (__bf16)v;
                }
            }
            int grow = grow0 + wm * 128 + i * 16 + lrow;
            bf16x8 v0 = *(const bf16x8*)&stg[lrow * 72 + (lane & 3) * 16];
            bf16x8 v1 = *(const bf16x8*)&stg[lrow * 72 + (lane & 3) * 16 + 8];
            __bf16* dst = Y + (size_t)grow * DIM + nb + wn * 64 + (lane & 3) * 16;
            *(bf16x8*)dst = v0;
            *(bf16x8*)(dst + 8) = v1;
        }
        __syncthreads();
    }
}

// ---------------------------------------------------------------------------
// Combine: out[t,:] = sum_j w_j * (Y0[g_j,:] + Y1[g_j,:])
// ---------------------------------------------------------------------------
__global__ __launch_bounds__(256)
void moe_combine(const __bf16* __restrict__ Y0,
                 const __bf16* __restrict__ Y1,
                 const int*    __restrict__ slot,
                 const float*  __restrict__ tw,
                 const int*    __restrict__ topk_p,
                 const int*    __restrict__ hdr,
                 float* __restrict__ out) {
    const int t = blockIdx.x;
    const int c = threadIdx.x * 4;
    int k = topk_p[0];
    if (k < 1) k = 1;
    if (k > NEXP) k = NEXP;
    float a0 = 0.f, a1 = 0.f, a2 = 0.f, a3 = 0.f;
    for (int j = 0; j < k; ++j) {
        int s = slot[t * 8 + j];
        int e = s >> 12, pos = s & 4095;
        int g = hdr[16 + e] + pos;
        float w = tw[t * 8 + j];
        bf16x4 y0 = *(const bf16x4*)&Y0[(size_t)g * DIM + c];
        bf16x4 y1 = *(const bf16x4*)&Y1[(size_t)g * DIM + c];
        a0 += w * ((float)y0[0] + (float)y1[0]);
        a1 += w * ((float)y0[1] + (float)y1[1]);
        a2 += w * ((float)y0[2] + (float)y1[2]);
        a3 += w * ((float)y0[3] + (float)y1[3]);
    }
    float4 o = {a0, a1, a2, a3};
    *(float4*)&out[(size_t)t * DIM + c] = o;
}

extern "C" void kernel_launch(void* const* d_in, const int* in_sizes, int n_in,
                              void* d_out, int out_size, void* d_ws, size_t ws_size,
                              hipStream_t stream) {
    const float* x  = (const float*)d_in[0];
    const float* gw = (const float*)d_in[1];
    const float* gb = (const float*)d_in[2];
    const float* w1 = (const float*)d_in[3];
    const float* b1 = (const float*)d_in[4];
    const float* w2 = (const float*)d_in[5];
    const float* b2 = (const float*)d_in[6];
    const int* topk = (const int*)d_in[7];
    float* out = (float*)d_out;

    char* ws = (char*)d_ws;
    size_t off = 0;
    int* counts = (int*)(ws + off);    off += 256;
    int* bucket = (int*)(ws + off);    off += (size_t)NEXP * T_TOK * 4;   // 128KB
    int* slot   = (int*)(ws + off);    off += (size_t)T_TOK * 8 * 4;      // 128KB
    float* tw   = (float*)(ws + off);  off += (size_t)T_TOK * 8 * 4;      // 128KB
    int* hdr    = (int*)(ws + off);    off += 4096;
    off = (off + 255) & ~(size_t)255;
    __bf16* xb  = (__bf16*)(ws + off); off += (size_t)T_TOK * DIM * 2;        // 8MB
    __bf16* w1t = (__bf16*)(ws + off); off += (size_t)NEXP * DIM * FDIM * 2;  // 64MB
    __bf16* w2t = (__bf16*)(ws + off); off += (size_t)NEXP * FDIM * DIM * 2;  // 64MB
    __bf16* H   = (__bf16*)(ws + off); off += (size_t)PADROWS * FDIM * 2;     // 80MB
    __bf16* Y0  = (__bf16*)(ws + off); off += (size_t)PADROWS * DIM * 2;      // 20MB
    __bf16* Y1  = (__bf16*)(ws + off);                                        // 20MB

    hipMemsetAsync(counts, 0, 256, stream);

    moe_router<<<T_TOK, 64, 0, stream>>>(x, gw, gb, topk, counts, bucket, slot, tw, xb);
    transpose_cvt<<<dim3(FDIM/64, DIM/64, NEXP), 256, 0, stream>>>(w1, w1t, DIM, FDIM);
    transpose_cvt<<<dim3(DIM/64, FDIM/64, NEXP), 256, 0, stream>>>(w2, w2t, FDIM, DIM);
    build_work<<<1, 64, 0, stream>>>(counts, hdr);

    moe_gemm1<<<512, 512, 0, stream>>>(xb, w1t, b1, counts, bucket, hdr, H);
    moe_gemm2<<<512, 512, 0, stream>>>(H, w2t, b2, hdr, Y0, Y1);
    moe_combine<<<T_TOK, 256, 0, stream>>>(Y0, Y1, slot, tw, topk, hdr, out);
}

// Round 7
// 724.470 us; speedup vs baseline: 1.1691x; 1.1691x over previous
//
#include <hip/hip_runtime.h>

// B=2,S=2048 -> T=4096 tokens, D=1024, F=4096, E=8; top_k on device.
// fp32 I/O; bf16 MFMA compute (fp32 accumulate).
// R12: revert GEMMs to verified-best R6 structure (128x128 tiles, BK=64,
// launch_bounds(256,4), gemm2 split-K x2 atomic; 725us total, 415us in
// GEMMs). New: fully-coalesced transpose_cvt (128x64 tile, 256B read AND
// write segments) to reclaim the ~290us the old 64x64 transpose burned.
#define T_TOK 4096
#define DIM   1024
#define FDIM  4096
#define NEXP  8

typedef __bf16 bf16x8 __attribute__((ext_vector_type(8)));
typedef __bf16 bf16x4 __attribute__((ext_vector_type(4)));
typedef float  f32x4  __attribute__((ext_vector_type(4)));

__device__ __forceinline__ void glds16(const void* g, void* l) {
    __builtin_amdgcn_global_load_lds(
        (const __attribute__((address_space(1))) void*)g,
        (__attribute__((address_space(3))) void*)l, 16, 0, 0);
}

// Bijective XCD-chunking swizzle (m204).
__device__ __forceinline__ int xcd_swz(int phys, int total) {
    int q = total >> 3, r = total & 7;
    int x = phys & 7, i = phys >> 3;
    return (x < r ? x * (q + 1) : r * (q + 1) + (x - r) * q) + i;
}

// ---------------------------------------------------------------------------
// Router (+ x->bf16 convert): one wave per token.
// ---------------------------------------------------------------------------
__global__ __launch_bounds__(64)
void moe_router(const float* __restrict__ x,
                const float* __restrict__ gw,
                const float* __restrict__ gb,
                const int*   __restrict__ topk_p,
                int*   __restrict__ counts,
                int*   __restrict__ bucket,
                float* __restrict__ bweight,
                __bf16* __restrict__ xb) {
    const int t = blockIdx.x;
    const int lane = threadIdx.x;
    float part[NEXP];
#pragma unroll
    for (int e = 0; e < NEXP; ++e) part[e] = 0.f;
    const float* xrow = x + (size_t)t * DIM;
    __bf16* xbrow = xb + (size_t)t * DIM;
#pragma unroll
    for (int r = 0; r < 4; ++r) {
        int c = r * 256 + lane * 4;
        float4 v = *(const float4*)&xrow[c];
        bf16x4 o; o[0]=(__bf16)v.x; o[1]=(__bf16)v.y; o[2]=(__bf16)v.z; o[3]=(__bf16)v.w;
        *(bf16x4*)&xbrow[c] = o;
#pragma unroll
        for (int e = 0; e < NEXP; ++e) {
            float4 g = *(const float4*)&gw[e * DIM + c];
            part[e] += v.x*g.x + v.y*g.y + v.z*g.z + v.w*g.w;
        }
    }
#pragma unroll
    for (int off = 32; off > 0; off >>= 1) {
#pragma unroll
        for (int e = 0; e < NEXP; ++e) part[e] += __shfl_xor(part[e], off);
    }
    if (lane == 0) {
        int k = topk_p[0];
        if (k < 1) k = 1;
        if (k > NEXP) k = NEXP;
        float p[NEXP];
        float mx = -1e30f;
#pragma unroll
        for (int e = 0; e < NEXP; ++e) {
            p[e] = part[e] + gb[e];
            mx = fmaxf(mx, p[e]);
        }
#pragma unroll
        for (int e = 0; e < NEXP; ++e) p[e] = __expf(p[e] - mx);
        bool used[NEXP];
#pragma unroll
        for (int e = 0; e < NEXP; ++e) used[e] = false;
        int sel[NEXP]; float selp[NEXP]; float wsum = 0.f;
        for (int j = 0; j < k; ++j) {
            int best = 0; float bv = -1.f;
            for (int e = 0; e < NEXP; ++e)
                if (!used[e] && p[e] > bv) { bv = p[e]; best = e; }  // ties->low idx
            used[best] = true; sel[j] = best; selp[j] = bv; wsum += bv;
        }
        for (int j = 0; j < k; ++j) {
            int e = sel[j];
            int pos = atomicAdd(&counts[e], 1);
            bucket[e * T_TOK + pos]  = t;
            bweight[e * T_TOK + pos] = selp[j] / wsum;
        }
    }
}

// ---------------------------------------------------------------------------
// Transpose+convert: in [z][R][C] fp32 -> out [z][C][R] bf16.
// Tile: 128 R-rows x 64 C-cols. Reads: 16 lanes x float4 = 256B segments.
// Writes: 16 lanes x bf16x8 = 256B segments. LDS [64][129] fp32 (33KB).
// ---------------------------------------------------------------------------
__global__ __launch_bounds__(256)
void transpose_cvt(const float* __restrict__ in, __bf16* __restrict__ out,
                   int R, int C) {
    const size_t zo = (size_t)blockIdx.z * R * C;
    in += zo; out += zo;
    __shared__ float ts[64][129];
    const int r0 = blockIdx.x * 128, c0 = blockIdx.y * 64;
    const int t = threadIdx.x;
    const int rr = t >> 4;            // 0..15 row within pass
    const int cl = (t & 15) * 4;      // float4 col within 64
    float4 v[8];
#pragma unroll
    for (int p = 0; p < 8; ++p)
        v[p] = *(const float4*)&in[(size_t)(r0 + p * 16 + rr) * C + c0 + cl];
#pragma unroll
    for (int p = 0; p < 8; ++p) {
        ts[cl + 0][p * 16 + rr] = v[p].x;
        ts[cl + 1][p * 16 + rr] = v[p].y;
        ts[cl + 2][p * 16 + rr] = v[p].z;
        ts[cl + 3][p * 16 + rr] = v[p].w;
    }
    __syncthreads();
    const int oc = t >> 4;            // 0..15 c-row within pass
    const int orc = (t & 15) * 8;     // 8-elem chunk within 128
#pragma unroll
    for (int p = 0; p < 4; ++p) {
        bf16x8 o;
#pragma unroll
        for (int j = 0; j < 8; ++j) o[j] = (__bf16)ts[p * 16 + oc][orc + j];
        *(bf16x8*)&out[(size_t)(c0 + p * 16 + oc) * R + r0 + orc] = o;
    }
}

// ---------------------------------------------------------------------------
// Work list: one list of (e, tile128) entries; hdr[0]=n, entries at hdr+8.
// ---------------------------------------------------------------------------
__global__ __launch_bounds__(64)
void build_work(const int* __restrict__ counts, int* __restrict__ hdr) {
    __shared__ int off1[NEXP + 1];
    const int lane = threadIdx.x;
    if (lane == 0) {
        int a = 0;
        for (int e = 0; e < NEXP; ++e) {
            off1[e] = a;
            a += (counts[e] + 127) >> 7;
        }
        off1[NEXP] = a;
        hdr[0] = a;
    }
    __syncthreads();
    for (int e = 0; e < NEXP; ++e) {
        int n1 = off1[e + 1] - off1[e];
        for (int j = lane; j < n1; j += 64) hdr[8 + off1[e] + j] = (e << 16) | j;
    }
}

// Shared tile geometry: A/B each 2 sub-tiles [128 rows][32 elems] (64 B rows).
//   A sub-tile kk at elem offset kk*4096;  B at 8192 + kk*4096.

// ---------------------------------------------------------------------------
// GEMM1: H[e,pos,f] = silu( xb[tok].W1T[e][f][:] + b1[e][f] )   128x128, BK=64
// ---------------------------------------------------------------------------
__global__ __launch_bounds__(256, 4)
void moe_gemm1(const __bf16* __restrict__ xb,
               const __bf16* __restrict__ w1t,   // [E][F][D]
               const float*  __restrict__ b1,
               const int*    __restrict__ counts,
               const int*    __restrict__ bucket,
               const int*    __restrict__ hdr,
               __bf16* __restrict__ H) {
    __shared__ __bf16 smem[16384];               // 32 KB
    __shared__ int tok_s[128];
    const int tid = threadIdx.x;
    const int wave = tid >> 6, lane = tid & 63;
    const int wm = wave & 1, wn = wave >> 1;
    const int quad = lane >> 4, l15 = lane & 15;
    const int lrow = lane >> 2;                  // 0..15: row within 16-row group
    const int lk8  = (lane & 3) * 8;             // elem offset within 64-elem row
    char* sb = (char*)smem;
    char* dA0 = sb + wave * 2048;                // kk=0, rows wave*32..+15
    char* dA1 = sb + 8192 + wave * 2048;         // kk=1
    char* dB0 = sb + 16384 + wave * 2048;
    char* dB1 = sb + 24576 + wave * 2048;

    const int n1 = hdr[0];
    const int total = n1 * (FDIM / 128);
    for (int phys = blockIdx.x; phys < total; phys += gridDim.x) {
        const int u = xcd_swz(phys, total);
        const int entry = hdr[8 + (u % n1)];
        const int e = entry >> 16, tile = entry & 0xffff;
        const int nb = (u / n1) * 128;
        const int cnt = counts[e];
        if (tid < 128) {
            int r = tile * 128 + tid;
            if (r >= cnt) r = cnt - 1;
            tok_s[tid] = bucket[e * T_TOK + r];
        }
        __syncthreads();

        const int ar0 = wave * 32 + lrow;
        const __bf16* pA0 = xb + (size_t)tok_s[ar0]      * DIM + lk8;
        const __bf16* pA1 = xb + (size_t)tok_s[ar0 + 16] * DIM + lk8;
        const __bf16* pB0 = w1t + ((size_t)e * FDIM + nb + wave * 32 + lrow) * DIM + lk8;
        const __bf16* pB1 = pB0 + (size_t)16 * DIM;

        f32x4 acc[4][4];
#pragma unroll
        for (int i = 0; i < 4; ++i)
#pragma unroll
            for (int j = 0; j < 4; ++j) acc[i][j] = (f32x4){0.f,0.f,0.f,0.f};

        for (int k0 = 0; k0 < DIM; k0 += 64) {
            glds16(pA0 + k0,      dA0);
            glds16(pA0 + k0 + 32, dA1);
            glds16(pA1 + k0,      dA0 + 1024);
            glds16(pA1 + k0 + 32, dA1 + 1024);
            glds16(pB0 + k0,      dB0);
            glds16(pB0 + k0 + 32, dB1);
            glds16(pB1 + k0,      dB0 + 1024);
            glds16(pB1 + k0 + 32, dB1 + 1024);
            __syncthreads();
#pragma unroll
            for (int kk = 0; kk < 2; ++kk) {
                bf16x8 af[4], bfr[4];
#pragma unroll
                for (int i = 0; i < 4; ++i)
                    af[i] = *(const bf16x8*)&smem[kk*4096 + (wm*64 + i*16 + l15)*32 + quad*8];
#pragma unroll
                for (int j = 0; j < 4; ++j)
                    bfr[j] = *(const bf16x8*)&smem[8192 + kk*4096 + (wn*64 + j*16 + l15)*32 + quad*8];
#pragma unroll
                for (int i = 0; i < 4; ++i)
#pragma unroll
                    for (int j = 0; j < 4; ++j)
                        acc[i][j] = __builtin_amdgcn_mfma_f32_16x16x32_bf16(
                            af[i], bfr[j], acc[i][j], 0, 0, 0);
            }
            __syncthreads();
        }

        // Epilogue: wave-private LDS transpose (stride 72 elems, 16B-aligned)
        // -> b128 H stores. No block barriers inside.
        __bf16* stg = (__bf16*)(sb + wave * 2304);
        const float* b1e = b1 + e * FDIM + nb + wn * 64;
#pragma unroll
        for (int i = 0; i < 4; ++i) {
#pragma unroll
            for (int j = 0; j < 4; ++j) {
                float bias = b1e[j * 16 + l15];
#pragma unroll
                for (int r = 0; r < 4; ++r) {
                    float v = acc[i][j][r] + bias;
                    float s = v / (1.f + __expf(-v));   // silu
                    stg[(quad*4 + r) * 72 + j*16 + l15] = (__bf16)s;
                }
            }
            int prow = tile * 128 + wm * 64 + i * 16 + lrow;
            if (prow < cnt) {
                bf16x8 v0 = *(const bf16x8*)&stg[lrow * 72 + (lane & 3) * 16];
                bf16x8 v1 = *(const bf16x8*)&stg[lrow * 72 + (lane & 3) * 16 + 8];
                __bf16* dst = H + (size_t)(e * T_TOK + prow) * FDIM
                              + nb + wn * 64 + (lane & 3) * 16;
                *(bf16x8*)dst = v0;
                *(bf16x8*)(dst + 8) = v1;
            }
        }
        __syncthreads();   // protect smem/tok_s before next unit
    }
}

// ---------------------------------------------------------------------------
// GEMM2: out[tok,d] += w * ( H[e,pos,:].W2T[e][d][:] + b2[e][d] )
// 128x128 tiles, BK=64, 2-way split-K (each block reduces FDIM/2=2048).
// ---------------------------------------------------------------------------
#define KSPLIT 2
#define KHALF  (FDIM / KSPLIT)

__global__ __launch_bounds__(256, 4)
void moe_gemm2(const __bf16* __restrict__ H,
               const __bf16* __restrict__ w2t,   // [E][D][F]
               const float*  __restrict__ b2,
               const int*    __restrict__ counts,
               const int*    __restrict__ bucket,
               const float*  __restrict__ bweight,
               const int*    __restrict__ hdr,
               float* __restrict__ out) {
    __shared__ __bf16 smem[16384];
    __shared__ int   tok_s[128];
    __shared__ float w_s[128];
    const int tid = threadIdx.x;
    const int wave = tid >> 6, lane = tid & 63;
    const int wm = wave & 1, wn = wave >> 1;
    const int quad = lane >> 4, l15 = lane & 15;
    const int lrow = lane >> 2;
    const int lk8  = (lane & 3) * 8;
    char* sb = (char*)smem;
    char* dA0 = sb + wave * 2048;
    char* dA1 = sb + 8192 + wave * 2048;
    char* dB0 = sb + 16384 + wave * 2048;
    char* dB1 = sb + 24576 + wave * 2048;

    const int n1 = hdr[0];
    const int total = n1 * (DIM / 128) * KSPLIT;
    for (int phys = blockIdx.x; phys < total; phys += gridDim.x) {
        const int u = xcd_swz(phys, total);
        const int entry = hdr[8 + (u % n1)];
        const int e = entry >> 16, tile = entry & 0xffff;
        const int rest = u / n1;
        const int nb = (rest & 7) * 128;       // DIM/128 = 8 output blocks
        const int kc = rest >> 3;              // split-K chunk: 0 or 1
        const int cnt = counts[e];
        if (tid < 128) {
            int r  = tile * 128 + tid;
            int rc = r < cnt ? r : cnt - 1;
            tok_s[tid] = bucket[e * T_TOK + rc];
            w_s[tid]   = bweight[e * T_TOK + rc];
        }
        __syncthreads();

        // A rows (H) are contiguous positions — no gather needed.
        const size_t kbase = (size_t)kc * KHALF;
        const __bf16* pA0 = H + (size_t)(e * T_TOK + tile * 128 + wave * 32 + lrow) * FDIM
                              + kbase + lk8;
        const __bf16* pA1 = pA0 + (size_t)16 * FDIM;
        const __bf16* pB0 = w2t + ((size_t)e * DIM + nb + wave * 32 + lrow) * FDIM
                              + kbase + lk8;
        const __bf16* pB1 = pB0 + (size_t)16 * FDIM;

        f32x4 acc[4][4];
#pragma unroll
        for (int i = 0; i < 4; ++i)
#pragma unroll
            for (int j = 0; j < 4; ++j) acc[i][j] = (f32x4){0.f,0.f,0.f,0.f};

        for (int k0 = 0; k0 < KHALF; k0 += 64) {
            glds16(pA0 + k0,      dA0);
            glds16(pA0 + k0 + 32, dA1);
            glds16(pA1 + k0,      dA0 + 1024);
            glds16(pA1 + k0 + 32, dA1 + 1024);
            glds16(pB0 + k0,      dB0);
            glds16(pB0 + k0 + 32, dB1);
            glds16(pB1 + k0,      dB0 + 1024);
            glds16(pB1 + k0 + 32, dB1 + 1024);
            __syncthreads();
#pragma unroll
            for (int kk = 0; kk < 2; ++kk) {
                bf16x8 af[4], bfr[4];
#pragma unroll
                for (int i = 0; i < 4; ++i)
                    af[i] = *(const bf16x8*)&smem[kk*4096 + (wm*64 + i*16 + l15)*32 + quad*8];
#pragma unroll
                for (int j = 0; j < 4; ++j)
                    bfr[j] = *(const bf16x8*)&smem[8192 + kk*4096 + (wn*64 + j*16 + l15)*32 + quad*8];
#pragma unroll
                for (int i = 0; i < 4; ++i)
#pragma unroll
                    for (int j = 0; j < 4; ++j)
                        acc[i][j] = __builtin_amdgcn_mfma_f32_16x16x32_bf16(
                            af[i], bfr[j], acc[i][j], 0, 0, 0);
            }
            __syncthreads();
        }

#pragma unroll
        for (int i = 0; i < 4; ++i)
#pragma unroll
            for (int j = 0; j < 4; ++j)
#pragma unroll
                for (int r = 0; r < 4; ++r) {
                    int m = wm*64 + i*16 + quad*4 + r;
                    int prow = tile * 128 + m;
                    if (prow < cnt) {
                        int dc = nb + wn*64 + j*16 + l15;
                        float v = acc[i][j][r] + (kc == 0 ? b2[e * DIM + dc] : 0.f);
                        atomicAdd(&out[(size_t)tok_s[m] * DIM + dc], w_s[m] * v);
                    }
                }
        __syncthreads();   // protect tok_s/w_s before next unit
    }
}

extern "C" void kernel_launch(void* const* d_in, const int* in_sizes, int n_in,
                              void* d_out, int out_size, void* d_ws, size_t ws_size,
                              hipStream_t stream) {
    const float* x  = (const float*)d_in[0];
    const float* gw = (const float*)d_in[1];
    const float* gb = (const float*)d_in[2];
    const float* w1 = (const float*)d_in[3];
    const float* b1 = (const float*)d_in[4];
    const float* w2 = (const float*)d_in[5];
    const float* b2 = (const float*)d_in[6];
    const int* topk = (const int*)d_in[7];
    float* out = (float*)d_out;

    char* ws = (char*)d_ws;
    size_t off = 0;
    int* counts = (int*)(ws + off);    off += 256;
    int* bucket = (int*)(ws + off);    off += (size_t)NEXP * T_TOK * 4;
    float* bw   = (float*)(ws + off);  off += (size_t)NEXP * T_TOK * 4;
    int* hdr    = (int*)(ws + off);    off += 4096;
    off = (off + 255) & ~(size_t)255;
    __bf16* xb  = (__bf16*)(ws + off); off += (size_t)T_TOK * DIM * 2;        // 8MB
    __bf16* w1t = (__bf16*)(ws + off); off += (size_t)NEXP * DIM * FDIM * 2;  // 64MB
    __bf16* w2t = (__bf16*)(ws + off); off += (size_t)NEXP * FDIM * DIM * 2;  // 64MB
    __bf16* H   = (__bf16*)(ws + off);                                        // 256MB

    hipMemsetAsync(counts, 0, 256, stream);
    hipMemsetAsync(out, 0, (size_t)out_size * 4, stream);

    moe_router<<<T_TOK, 64, 0, stream>>>(x, gw, gb, topk, counts, bucket, bw, xb);
    // in [z][R][C] -> out [z][C][R]; tile 128(R) x 64(C)
    transpose_cvt<<<dim3(DIM/128, FDIM/64, NEXP), 256, 0, stream>>>(w1, w1t, DIM, FDIM);
    transpose_cvt<<<dim3(FDIM/128, DIM/64, NEXP), 256, 0, stream>>>(w2, w2t, FDIM, DIM);
    build_work<<<1, 64, 0, stream>>>(counts, hdr);

    moe_gemm1<<<2048, 256, 0, stream>>>(xb, w1t, b1, counts, bucket, hdr, H);
    moe_gemm2<<<1024, 256, 0, stream>>>(H, w2t, b2, counts, bucket, bw, hdr, out);
}

// Round 8
// 720.626 us; speedup vs baseline: 1.1753x; 1.0053x over previous
//
#include <hip/hip_runtime.h>

// B=2,S=2048 -> T=4096 tokens, D=1024, F=4096, E=8; top_k on device.
// fp32 I/O; bf16 MFMA compute (fp32 accumulate).
// R13: R12 GEMMs converted to 2-phase double-buffer: BK=32, 2x16KB LDS
// buffers, stage tile t+1 BEFORE computing tile t, ONE __syncthreads per
// K-step (its vmcnt(0) drain covers loads issued a compute-phase earlier).
// Fragment reads are clobber-free asm ds_read_b128 (R10-verified) so the
// compiler inserts no extra drains. Everything else identical to R12.
#define T_TOK 4096
#define DIM   1024
#define FDIM  4096
#define NEXP  8

typedef __bf16 bf16x8 __attribute__((ext_vector_type(8)));
typedef __bf16 bf16x4 __attribute__((ext_vector_type(4)));
typedef float  f32x4  __attribute__((ext_vector_type(4)));
typedef const __attribute__((address_space(3))) char* lds3;

__device__ __forceinline__ void glds16(const void* g, void* l) {
    __builtin_amdgcn_global_load_lds(
        (const __attribute__((address_space(1))) void*)g,
        (__attribute__((address_space(3))) void*)l, 16, 0, 0);
}

// Clobber-free (R9/R10 lesson): no "memory" clobber => no compiler-inserted
// vmcnt drains before the reads; data ordering via lgkmcnt(0)+sched_barrier.
#define DSR(dst, a, imm) \
    asm volatile("ds_read_b128 %0, %1 offset:" #imm : "=v"(dst) : "v"(a))

// Bijective XCD-chunking swizzle (m204).
__device__ __forceinline__ int xcd_swz(int phys, int total) {
    int q = total >> 3, r = total & 7;
    int x = phys & 7, i = phys >> 3;
    return (x < r ? x * (q + 1) : r * (q + 1) + (x - r) * q) + i;
}

// ---------------------------------------------------------------------------
// Router (+ x->bf16 convert): one wave per token.
// ---------------------------------------------------------------------------
__global__ __launch_bounds__(64)
void moe_router(const float* __restrict__ x,
                const float* __restrict__ gw,
                const float* __restrict__ gb,
                const int*   __restrict__ topk_p,
                int*   __restrict__ counts,
                int*   __restrict__ bucket,
                float* __restrict__ bweight,
                __bf16* __restrict__ xb) {
    const int t = blockIdx.x;
    const int lane = threadIdx.x;
    float part[NEXP];
#pragma unroll
    for (int e = 0; e < NEXP; ++e) part[e] = 0.f;
    const float* xrow = x + (size_t)t * DIM;
    __bf16* xbrow = xb + (size_t)t * DIM;
#pragma unroll
    for (int r = 0; r < 4; ++r) {
        int c = r * 256 + lane * 4;
        float4 v = *(const float4*)&xrow[c];
        bf16x4 o; o[0]=(__bf16)v.x; o[1]=(__bf16)v.y; o[2]=(__bf16)v.z; o[3]=(__bf16)v.w;
        *(bf16x4*)&xbrow[c] = o;
#pragma unroll
        for (int e = 0; e < NEXP; ++e) {
            float4 g = *(const float4*)&gw[e * DIM + c];
            part[e] += v.x*g.x + v.y*g.y + v.z*g.z + v.w*g.w;
        }
    }
#pragma unroll
    for (int off = 32; off > 0; off >>= 1) {
#pragma unroll
        for (int e = 0; e < NEXP; ++e) part[e] += __shfl_xor(part[e], off);
    }
    if (lane == 0) {
        int k = topk_p[0];
        if (k < 1) k = 1;
        if (k > NEXP) k = NEXP;
        float p[NEXP];
        float mx = -1e30f;
#pragma unroll
        for (int e = 0; e < NEXP; ++e) {
            p[e] = part[e] + gb[e];
            mx = fmaxf(mx, p[e]);
        }
#pragma unroll
        for (int e = 0; e < NEXP; ++e) p[e] = __expf(p[e] - mx);
        bool used[NEXP];
#pragma unroll
        for (int e = 0; e < NEXP; ++e) used[e] = false;
        int sel[NEXP]; float selp[NEXP]; float wsum = 0.f;
        for (int j = 0; j < k; ++j) {
            int best = 0; float bv = -1.f;
            for (int e = 0; e < NEXP; ++e)
                if (!used[e] && p[e] > bv) { bv = p[e]; best = e; }  // ties->low idx
            used[best] = true; sel[j] = best; selp[j] = bv; wsum += bv;
        }
        for (int j = 0; j < k; ++j) {
            int e = sel[j];
            int pos = atomicAdd(&counts[e], 1);
            bucket[e * T_TOK + pos]  = t;
            bweight[e * T_TOK + pos] = selp[j] / wsum;
        }
    }
}

// ---------------------------------------------------------------------------
// Transpose+convert: in [z][R][C] fp32 -> out [z][C][R] bf16.
// Tile: 128 R-rows x 64 C-cols; 256B read and write segments.
// ---------------------------------------------------------------------------
__global__ __launch_bounds__(256)
void transpose_cvt(const float* __restrict__ in, __bf16* __restrict__ out,
                   int R, int C) {
    const size_t zo = (size_t)blockIdx.z * R * C;
    in += zo; out += zo;
    __shared__ float ts[64][129];
    const int r0 = blockIdx.x * 128, c0 = blockIdx.y * 64;
    const int t = threadIdx.x;
    const int rr = t >> 4;            // 0..15 row within pass
    const int cl = (t & 15) * 4;      // float4 col within 64
    float4 v[8];
#pragma unroll
    for (int p = 0; p < 8; ++p)
        v[p] = *(const float4*)&in[(size_t)(r0 + p * 16 + rr) * C + c0 + cl];
#pragma unroll
    for (int p = 0; p < 8; ++p) {
        ts[cl + 0][p * 16 + rr] = v[p].x;
        ts[cl + 1][p * 16 + rr] = v[p].y;
        ts[cl + 2][p * 16 + rr] = v[p].z;
        ts[cl + 3][p * 16 + rr] = v[p].w;
    }
    __syncthreads();
    const int oc = t >> 4;            // 0..15 c-row within pass
    const int orc = (t & 15) * 8;     // 8-elem chunk within 128
#pragma unroll
    for (int p = 0; p < 4; ++p) {
        bf16x8 o;
#pragma unroll
        for (int j = 0; j < 8; ++j) o[j] = (__bf16)ts[p * 16 + oc][orc + j];
        *(bf16x8*)&out[(size_t)(c0 + p * 16 + oc) * R + r0 + orc] = o;
    }
}

// ---------------------------------------------------------------------------
// Work list: one list of (e, tile128) entries; hdr[0]=n, entries at hdr+8.
// ---------------------------------------------------------------------------
__global__ __launch_bounds__(64)
void build_work(const int* __restrict__ counts, int* __restrict__ hdr) {
    __shared__ int off1[NEXP + 1];
    const int lane = threadIdx.x;
    if (lane == 0) {
        int a = 0;
        for (int e = 0; e < NEXP; ++e) {
            off1[e] = a;
            a += (counts[e] + 127) >> 7;
        }
        off1[NEXP] = a;
        hdr[0] = a;
    }
    __syncthreads();
    for (int e = 0; e < NEXP; ++e) {
        int n1 = off1[e + 1] - off1[e];
        for (int j = lane; j < n1; j += 64) hdr[8 + off1[e] + j] = (e << 16) | j;
    }
}

// ---------------------------------------------------------------------------
// 2-phase GEMM machinery. Per buffer (16KB): A[128 rows][32 elems] at byte 0
// (row=64B), B[128][32] at byte 8192. Buffers at sb+0 / sb+16384.
// K-step: STAGE(next buf) -> 8 asm ds_read_b128 (cur buf) -> lgkmcnt(0) ->
// 16 MFMA (setprio) -> __syncthreads (drain covers the stage issued one
// compute-phase earlier).
// ---------------------------------------------------------------------------
#define STAGE(DST, KO) do { \
    glds16(pA0 + (KO), (DST)); \
    glds16(pA1 + (KO), (DST) + 1024); \
    glds16(pB0 + (KO), (DST) + 8192); \
    glds16(pB1 + (KO), (DST) + 9216); } while (0)

#define PHASE(APTR, BPTR) do { \
    bf16x8 af[4], bfr[4]; \
    DSR(af[0], (APTR), 0);    DSR(af[1], (APTR), 1024); \
    DSR(af[2], (APTR), 2048); DSR(af[3], (APTR), 3072); \
    DSR(bfr[0], (BPTR), 0);    DSR(bfr[1], (BPTR), 1024); \
    DSR(bfr[2], (BPTR), 2048); DSR(bfr[3], (BPTR), 3072); \
    asm volatile("s_waitcnt lgkmcnt(0)"); \
    __builtin_amdgcn_sched_barrier(0); \
    __builtin_amdgcn_s_setprio(1); \
    _Pragma("unroll") for (int i_ = 0; i_ < 4; ++i_) \
    _Pragma("unroll") for (int j_ = 0; j_ < 4; ++j_) \
        acc[i_][j_] = __builtin_amdgcn_mfma_f32_16x16x32_bf16( \
            af[i_], bfr[j_], acc[i_][j_], 0, 0, 0); \
    __builtin_amdgcn_s_setprio(0); \
    __builtin_amdgcn_sched_barrier(0); \
    __syncthreads(); } while (0)

#define KLOOP2(NT) do { \
    STAGE(stg0, 0); \
    __syncthreads(); \
    _Pragma("unroll 1") \
    for (int t_ = 0; t_ < (NT); t_ += 2) { \
        STAGE(stg1, (t_ + 1) * 32); \
        PHASE(aP0, bP0); \
        if (t_ + 2 < (NT)) STAGE(stg0, (t_ + 2) * 32); \
        PHASE(aP1, bP1); \
    } } while (0)

#define GEMM_LANES \
    const int tid = threadIdx.x; \
    const int wave = tid >> 6, lane = tid & 63; \
    const int wm = wave & 1, wn = wave >> 1; \
    const int quad = lane >> 4, l15 = lane & 15; \
    const int lrow = lane >> 2; \
    const int lk8  = (lane & 3) * 8; \
    char* stg0 = sb + wave * 2048; \
    char* stg1 = stg0 + 16384; \
    lds3 s3 = (lds3)sb; \
    lds3 aP0 = s3 + (wm * 64 + l15) * 64 + quad * 16; \
    lds3 bP0 = s3 + 8192 + (wn * 64 + l15) * 64 + quad * 16; \
    lds3 aP1 = aP0 + 16384; \
    lds3 bP1 = bP0 + 16384;

// ---------------------------------------------------------------------------
// GEMM1: H[e,pos,f] = silu( xb[tok].W1T[e][f][:] + b1[e][f] )   128x128, BK=32
// ---------------------------------------------------------------------------
__global__ __launch_bounds__(256, 4)
void moe_gemm1(const __bf16* __restrict__ xb,
               const __bf16* __restrict__ w1t,   // [E][F][D]
               const float*  __restrict__ b1,
               const int*    __restrict__ counts,
               const int*    __restrict__ bucket,
               const int*    __restrict__ hdr,
               __bf16* __restrict__ H) {
    __shared__ __align__(16) char sb[32768];     // 2 x 16KB
    __shared__ int tok_s[128];
    GEMM_LANES

    const int n1 = hdr[0];
    const int total = n1 * (FDIM / 128);
    for (int phys = blockIdx.x; phys < total; phys += gridDim.x) {
        const int u = xcd_swz(phys, total);
        const int entry = hdr[8 + (u % n1)];
        const int e = entry >> 16, tile = entry & 0xffff;
        const int nb = (u / n1) * 128;
        const int cnt = counts[e];
        if (tid < 128) {
            int r = tile * 128 + tid;
            if (r >= cnt) r = cnt - 1;
            tok_s[tid] = bucket[e * T_TOK + r];
        }
        __syncthreads();

        const int ar0 = wave * 32 + lrow;
        const __bf16* pA0 = xb + (size_t)tok_s[ar0]      * DIM + lk8;
        const __bf16* pA1 = xb + (size_t)tok_s[ar0 + 16] * DIM + lk8;
        const __bf16* pB0 = w1t + ((size_t)e * FDIM + nb + wave * 32 + lrow) * DIM + lk8;
        const __bf16* pB1 = pB0 + (size_t)16 * DIM;

        f32x4 acc[4][4];
#pragma unroll
        for (int i = 0; i < 4; ++i)
#pragma unroll
            for (int j = 0; j < 4; ++j) acc[i][j] = (f32x4){0.f,0.f,0.f,0.f};

        KLOOP2(DIM / 32);   // 32 K-steps

        // Epilogue: wave-private LDS transpose (stride 72 elems, 16B-aligned)
        // -> b128 H stores. No block barriers inside.
        __bf16* stg = (__bf16*)(sb + wave * 2304);
        const float* b1e = b1 + e * FDIM + nb + wn * 64;
#pragma unroll
        for (int i = 0; i < 4; ++i) {
#pragma unroll
            for (int j = 0; j < 4; ++j) {
                float bias = b1e[j * 16 + l15];
#pragma unroll
                for (int r = 0; r < 4; ++r) {
                    float v = acc[i][j][r] + bias;
                    float s = v / (1.f + __expf(-v));   // silu
                    stg[(quad*4 + r) * 72 + j*16 + l15] = (__bf16)s;
                }
            }
            int prow = tile * 128 + wm * 64 + i * 16 + lrow;
            if (prow < cnt) {
                bf16x8 v0 = *(const bf16x8*)&stg[lrow * 72 + (lane & 3) * 16];
                bf16x8 v1 = *(const bf16x8*)&stg[lrow * 72 + (lane & 3) * 16 + 8];
                __bf16* dst = H + (size_t)(e * T_TOK + prow) * FDIM
                              + nb + wn * 64 + (lane & 3) * 16;
                *(bf16x8*)dst = v0;
                *(bf16x8*)(dst + 8) = v1;
            }
        }
        __syncthreads();   // protect smem/tok_s before next unit
    }
}

// ---------------------------------------------------------------------------
// GEMM2: out[tok,d] += w * ( H[e,pos,:].W2T[e][d][:] + b2[e][d] )
// 128x128 tiles, BK=32, 2-way split-K (each block reduces FDIM/2=2048).
// ---------------------------------------------------------------------------
#define KSPLIT 2
#define KHALF  (FDIM / KSPLIT)

__global__ __launch_bounds__(256, 4)
void moe_gemm2(const __bf16* __restrict__ H,
               const __bf16* __restrict__ w2t,   // [E][D][F]
               const float*  __restrict__ b2,
               const int*    __restrict__ counts,
               const int*    __restrict__ bucket,
               const float*  __restrict__ bweight,
               const int*    __restrict__ hdr,
               float* __restrict__ out) {
    __shared__ __align__(16) char sb[32768];
    __shared__ int   tok_s[128];
    __shared__ float w_s[128];
    GEMM_LANES

    const int n1 = hdr[0];
    const int total = n1 * (DIM / 128) * KSPLIT;
    for (int phys = blockIdx.x; phys < total; phys += gridDim.x) {
        const int u = xcd_swz(phys, total);
        const int entry = hdr[8 + (u % n1)];
        const int e = entry >> 16, tile = entry & 0xffff;
        const int rest = u / n1;
        const int nb = (rest & 7) * 128;       // DIM/128 = 8 output blocks
        const int kc = rest >> 3;              // split-K chunk: 0 or 1
        const int cnt = counts[e];
        if (tid < 128) {
            int r  = tile * 128 + tid;
            int rc = r < cnt ? r : cnt - 1;
            tok_s[tid] = bucket[e * T_TOK + rc];
            w_s[tid]   = bweight[e * T_TOK + rc];
        }
        __syncthreads();

        // A rows (H) are contiguous positions — no gather needed.
        const size_t kbase = (size_t)kc * KHALF;
        const __bf16* pA0 = H + (size_t)(e * T_TOK + tile * 128 + wave * 32 + lrow) * FDIM
                              + kbase + lk8;
        const __bf16* pA1 = pA0 + (size_t)16 * FDIM;
        const __bf16* pB0 = w2t + ((size_t)e * DIM + nb + wave * 32 + lrow) * FDIM
                              + kbase + lk8;
        const __bf16* pB1 = pB0 + (size_t)16 * FDIM;

        f32x4 acc[4][4];
#pragma unroll
        for (int i = 0; i < 4; ++i)
#pragma unroll
            for (int j = 0; j < 4; ++j) acc[i][j] = (f32x4){0.f,0.f,0.f,0.f};

        KLOOP2(KHALF / 32);   // 64 K-steps

#pragma unroll
        for (int i = 0; i < 4; ++i)
#pragma unroll
            for (int j = 0; j < 4; ++j)
#pragma unroll
                for (int r = 0; r < 4; ++r) {
                    int m = wm*64 + i*16 + quad*4 + r;
                    int prow = tile * 128 + m;
                    if (prow < cnt) {
                        int dc = nb + wn*64 + j*16 + l15;
                        float v = acc[i][j][r] + (kc == 0 ? b2[e * DIM + dc] : 0.f);
                        atomicAdd(&out[(size_t)tok_s[m] * DIM + dc], w_s[m] * v);
                    }
                }
        __syncthreads();   // protect tok_s/w_s before next unit
    }
}

extern "C" void kernel_launch(void* const* d_in, const int* in_sizes, int n_in,
                              void* d_out, int out_size, void* d_ws, size_t ws_size,
                              hipStream_t stream) {
    const float* x  = (const float*)d_in[0];
    const float* gw = (const float*)d_in[1];
    const float* gb = (const float*)d_in[2];
    const float* w1 = (const float*)d_in[3];
    const float* b1 = (const float*)d_in[4];
    const float* w2 = (const float*)d_in[5];
    const float* b2 = (const float*)d_in[6];
    const int* topk = (const int*)d_in[7];
    float* out = (float*)d_out;

    char* ws = (char*)d_ws;
    size_t off = 0;
    int* counts = (int*)(ws + off);    off += 256;
    int* bucket = (int*)(ws + off);    off += (size_t)NEXP * T_TOK * 4;
    float* bw   = (float*)(ws + off);  off += (size_t)NEXP * T_TOK * 4;
    int* hdr    = (int*)(ws + off);    off += 4096;
    off = (off + 255) & ~(size_t)255;
    __bf16* xb  = (__bf16*)(ws + off); off += (size_t)T_TOK * DIM * 2;        // 8MB
    __bf16* w1t = (__bf16*)(ws + off); off += (size_t)NEXP * DIM * FDIM * 2;  // 64MB
    __bf16* w2t = (__bf16*)(ws + off); off += (size_t)NEXP * FDIM * DIM * 2;  // 64MB
    __bf16* H   = (__bf16*)(ws + off);                                        // 256MB

    hipMemsetAsync(counts, 0, 256, stream);
    hipMemsetAsync(out, 0, (size_t)out_size * 4, stream);

    moe_router<<<T_TOK, 64, 0, stream>>>(x, gw, gb, topk, counts, bucket, bw, xb);
    // in [z][R][C] -> out [z][C][R]; tile 128(R) x 64(C)
    transpose_cvt<<<dim3(DIM/128, FDIM/64, NEXP), 256, 0, stream>>>(w1, w1t, DIM, FDIM);
    transpose_cvt<<<dim3(FDIM/128, DIM/64, NEXP), 256, 0, stream>>>(w2, w2t, FDIM, DIM);
    build_work<<<1, 64, 0, stream>>>(counts, hdr);

    moe_gemm1<<<2048, 256, 0, stream>>>(xb, w1t, b1, counts, bucket, hdr, H);
    moe_gemm2<<<1024, 256, 0, stream>>>(H, w2t, b2, counts, bucket, bw, hdr, out);
}